// Round 2
// 878.086 us; speedup vs baseline: 1.0299x; 1.0299x over previous
//
#include <hip/hip_runtime.h>
#include <cstdint>
#include <cstddef>

typedef unsigned short u16;
typedef short bf16x8 __attribute__((ext_vector_type(8)));
typedef float f32x4 __attribute__((ext_vector_type(4)));
typedef u16 u16x4 __attribute__((ext_vector_type(4)));

#define NTOK 8192
#define HID 1024
#define NEXP 8
#define FF 4096
#define MAXPAIR 18432   // 2*NTOK + 8*255 pad headroom (segments padded to 256)

__device__ __forceinline__ u16 bf16_rne(float f) {
  unsigned u = __builtin_bit_cast(unsigned, f);
  return (u16)((u + 0x7FFFu + ((u >> 16) & 1u)) >> 16);
}

__device__ __forceinline__ float gelu_tanh(float v) {
  const float u = 0.7978845608028654f * (v + 0.044715f * v * v * v);
  const float e = __expf(2.0f * u);          // inf-safe: e=inf -> v; e=0 -> 0
  return v - v * __frcp_rn(e + 1.0f);
}

__device__ __forceinline__ void async16(const void* g, void* l) {
  __builtin_amdgcn_global_load_lds(
      (const __attribute__((address_space(1))) void*)g,
      (__attribute__((address_space(3))) void*)l, 16, 0, 0);
}

// ---------------- gate: logits, top-2, softmax probs ----------------
__global__ __launch_bounds__(256) void gate_kernel(
    const float* __restrict__ x, const float* __restrict__ gw,
    const float* __restrict__ gb, int* __restrict__ counts,
    float* __restrict__ probs_sum, int* __restrict__ topk_e,
    float* __restrict__ topk_w) {
  __shared__ float sgw[NEXP * HID];
  __shared__ float sProbs[NEXP];
  __shared__ int sCnt[NEXP];
  const int tid = threadIdx.x;
  for (int i = tid; i < NEXP * HID; i += 256) sgw[i] = gw[i];
  if (tid < NEXP) { sProbs[tid] = 0.f; sCnt[tid] = 0; }
  __syncthreads();
  const int lane = tid & 63, wave = tid >> 6;
  for (int it = 0; it < 4; ++it) {
    const int t = blockIdx.x * 16 + wave * 4 + it;
    const float* xr = x + (size_t)t * HID;
    float a[NEXP];
#pragma unroll
    for (int e = 0; e < NEXP; ++e) a[e] = 0.f;
    for (int j = 0; j < 16; ++j) {
      const int o = lane + 64 * j;
      const float v = xr[o];
#pragma unroll
      for (int e = 0; e < NEXP; ++e) a[e] += v * sgw[e * HID + o];
    }
#pragma unroll
    for (int off = 32; off > 0; off >>= 1)
#pragma unroll
      for (int e = 0; e < NEXP; ++e) a[e] += __shfl_xor(a[e], off);
    if (lane == 0) {
      float l[NEXP];
#pragma unroll
      for (int e = 0; e < NEXP; ++e) l[e] = a[e] + gb[e];
      int b0 = 0; float v0 = l[0];
#pragma unroll
      for (int e = 1; e < NEXP; ++e) if (l[e] > v0) { b0 = e; v0 = l[e]; }
      int b1i = (b0 == 0) ? 1 : 0; float v1 = l[b1i];
#pragma unroll
      for (int e = 0; e < NEXP; ++e) if (e != b0 && l[e] > v1) { b1i = e; v1 = l[e]; }
      const float e1 = __expf(v1 - v0);
      const float inv01 = 1.f / (1.f + e1);
      topk_e[2 * t] = b0; topk_e[2 * t + 1] = b1i;
      topk_w[2 * t] = inv01; topk_w[2 * t + 1] = e1 * inv01;
      atomicAdd(&sCnt[b0], 1); atomicAdd(&sCnt[b1i], 1);
      float s = 0.f, p[NEXP];
#pragma unroll
      for (int e = 0; e < NEXP; ++e) { p[e] = __expf(l[e] - v0); s += p[e]; }
      const float invs = 1.f / s;
#pragma unroll
      for (int e = 0; e < NEXP; ++e) atomicAdd(&sProbs[e], p[e] * invs);
    }
  }
  __syncthreads();
  if (tid < NEXP) {
    atomicAdd(&counts[tid], sCnt[tid]);
    atomicAdd(&probs_sum[tid], sProbs[tid]);
  }
}

// ---------------- finalize: 256-padded prefix offsets + l_aux ----------------
__global__ void finalize_kernel(const int* __restrict__ counts,
                                int* __restrict__ cursors,
                                int* __restrict__ offsets,
                                const float* __restrict__ probs_sum,
                                float* __restrict__ laux) {
  if (threadIdx.x == 0) {
    int off = 0;
    for (int e = 0; e < NEXP; ++e) {
      offsets[e] = off;
      off += ((counts[e] + 255) / 256) * 256;   // pad to BM=256
      cursors[e] = 0;
    }
    offsets[NEXP] = off;
    float s = 0.f;
    for (int e = 0; e < NEXP; ++e) {
      const float p = probs_sum[e] * (1.f / (float)NTOK);
      s += p * p;
    }
    *laux = (float)NEXP * s;
  }
}

// ---------------- scatter tokens into per-expert pair lists ----------------
__global__ __launch_bounds__(256) void scatter_kernel(
    const int* __restrict__ topk_e, const float* __restrict__ topk_w,
    const int* __restrict__ offsets, int* __restrict__ cursors,
    int* __restrict__ tok_of_pair, float* __restrict__ wt_of_pair,
    int* __restrict__ slot_of_tok) {
  __shared__ int lcnt[NEXP], lbase[NEXP];
  const int tid = threadIdx.x;
  if (tid < NEXP) lcnt[tid] = 0;
  __syncthreads();
  const int t = blockIdx.x * 256 + tid;
  const int e0 = topk_e[2 * t], e1 = topk_e[2 * t + 1];
  const int p0 = atomicAdd(&lcnt[e0], 1);
  const int p1 = atomicAdd(&lcnt[e1], 1);
  __syncthreads();
  if (tid < NEXP) lbase[tid] = atomicAdd(&cursors[tid], lcnt[tid]);
  __syncthreads();
  const int s0 = offsets[e0] + lbase[e0] + p0;
  const int s1 = offsets[e1] + lbase[e1] + p1;
  tok_of_pair[s0] = t; wt_of_pair[s0] = topk_w[2 * t];
  tok_of_pair[s1] = t; wt_of_pair[s1] = topk_w[2 * t + 1];
  slot_of_tok[2 * t] = s0; slot_of_tok[2 * t + 1] = s1;
}

// ---------------- fp32 -> bf16 streaming convert ----------------
__global__ __launch_bounds__(256) void stream_cvt_kernel(const float4* __restrict__ src,
                                                         u16x4* __restrict__ dst) {
  const int i = blockIdx.x * 256 + threadIdx.x;
  const float4 v = src[i];
  u16x4 o;
  o[0] = bf16_rne(v.x); o[1] = bf16_rne(v.y); o[2] = bf16_rne(v.z); o[3] = bf16_rne(v.w);
  dst[i] = o;
}

// ============ 256x256-tile 8-wave lockstep GEMM (T2+T3+T4+T5 port) ==========
// Ring-4 of K=32 LDS slots; staging runs 2 K-steps ahead; per-step wait is
// s_waitcnt vmcnt(4) (counted, never 0 in steady state). Raw s_barrier (no
// compiler vmcnt(0) drain) + sched_barrier(0) pins; setprio(1) around MFMA.
//
// LDS geometry (proven-0-conflict from the 903us kernel): 128B physical rows
// hold TWO logical rows (r=2*prow+hi). Phys 16B-group g' stores logical group
// g = g' ^ (prow&7), where logical g = (hi<<2)|q, q = k-quarter (8 u16).
// Staging writes LINEAR phys slots (gload_lds requirement) from pre-swizzled
// GLOBAL source addresses; readers use per-lane-constant swizzled slots.
// Frag mapping (verified): lane=(q,nl): A/B row nl, k=q*8..+8; C/D col=nl,
// row=(lane>>4)*4+reg.
template <bool P1>
__global__ __launch_bounds__(512, 2) void moe_gemm(
    const u16* __restrict__ Aop,     // P1: xb [NTOK][HID]   P2: h [MAXPAIR][FF]
    const u16* __restrict__ Bop,     // P1: w1b [E][FF][HID] P2: w2b [E][HID][FF]
    const float* __restrict__ b1,    // P1 only
    const int* __restrict__ tok_of_pair,
    const int* __restrict__ offsets,
    u16* __restrict__ hout,          // P1 output
    float* __restrict__ ypair) {     // P2 output
  constexpr int LDK  = P1 ? HID : FF;   // K extent = A/B row stride
  constexpr int NOUT = P1 ? FF : HID;   // B rows per expert
  constexpr int T    = LDK / 32;        // K-steps
  __shared__ u16 As[4][8192];           // 4 x 16KB
  __shared__ u16 Bs[4][8192];           // 4 x 16KB  (total 128 KiB)
  const int nt = blockIdx.x, mt = blockIdx.y;
  const int base = mt * 256;
  if (base >= offsets[NEXP]) return;
  int e = 0;
  while (e < NEXP - 1 && base >= offsets[e + 1]) ++e;
  const int tid = threadIdx.x;
  const int lane = tid & 63;
  const int wave = tid >> 6;
  const int wm = wave & 1, wn = wave >> 1;     // 2M x 4N waves; per-wave 128x64

  // ---- staging: thread -> phys slot tid (and tid+512) -> logical (row,col)
  const int gl = (tid & 7) ^ ((tid >> 3) & 7);   // logical 16B group 0..7
  const int rS = ((tid >> 3) << 1) | (gl >> 2);  // logical row 0..127
  const int cS = (gl & 3) * 8;                   // k offset (u16) 0..24
  const u16 *gA0, *gA1;
  if constexpr (P1) {
    gA0 = Aop + (size_t)tok_of_pair[base + rS] * LDK + cS;
    gA1 = Aop + (size_t)tok_of_pair[base + rS + 128] * LDK + cS;
  } else {
    gA0 = Aop + (size_t)(base + rS) * LDK + cS;
    gA1 = Aop + (size_t)(base + rS + 128) * LDK + cS;
  }
  const u16* wBb = Bop + (size_t)e * ((size_t)NOUT * LDK) + (size_t)(nt * 256) * LDK;
  const u16* gB0 = wBb + (size_t)rS * LDK + cS;
  const u16* gB1 = wBb + (size_t)(rS + 128) * LDK + cS;

#define STAGE_A(step) { u16* d_ = &As[(step) & 3][0]; const int k_ = (step) * 32; \
    async16(gA0 + k_, d_ + (size_t)tid * 8); async16(gA1 + k_, d_ + ((size_t)tid + 512) * 8); }
#define STAGE_B(step) { u16* d_ = &Bs[(step) & 3][0]; const int k_ = (step) * 32; \
    async16(gB0 + k_, d_ + (size_t)tid * 8); async16(gB1 + k_, d_ + ((size_t)tid + 512) * 8); }

  // ---- prologue: steps 0,1 in flight; retire step 0 (8 outstanding -> 4) ----
  STAGE_A(0); STAGE_B(0); STAGE_A(1); STAGE_B(1);
  asm volatile("s_waitcnt vmcnt(4)" ::: "memory");
  __builtin_amdgcn_s_barrier();
  __builtin_amdgcn_sched_barrier(0);

  // ---- reader constants: per-lane swizzled 16B slot (2-way max = free) ----
  const int nl = lane & 15, q = lane >> 4;
  const int rdS = (((((nl & 1) << 2) | q) ^ (nl >> 1))) * 8;       // u16
  const int aB = (wm * 64 + (nl >> 1)) * 64 + rdS;  // A: row wm*128+nl, +i*512, +ph*2048
  const int bB = (wn * 32 + (nl >> 1)) * 64 + rdS;  // B: row wn*64+nl,  +j*512

  f32x4 acc[8][4];
#pragma unroll
  for (int i = 0; i < 8; ++i)
#pragma unroll
    for (int j = 0; j < 4; ++j) acc[i][j] = (f32x4){0.f, 0.f, 0.f, 0.f};

#pragma unroll 1
  for (int t = 0; t < T; ++t) {
    const u16* A = &As[t & 3][0];
    const u16* B = &Bs[t & 3][0];
    const bool pf = (t + 2 < T);
    bf16x8 af[4], bf[4];
    // ---------- phase 0: rows wm*128 + 0..63 ----------
#pragma unroll
    for (int i = 0; i < 4; ++i) af[i] = *(const bf16x8*)&A[aB + i * 512];
#pragma unroll
    for (int j = 0; j < 4; ++j) bf[j] = *(const bf16x8*)&B[bB + j * 512];
    if (pf) STAGE_A(t + 2);
    __builtin_amdgcn_s_barrier();
    __builtin_amdgcn_sched_barrier(0);
    __builtin_amdgcn_s_setprio(1);
#pragma unroll
    for (int i = 0; i < 4; ++i)
#pragma unroll
      for (int j = 0; j < 4; ++j)
        acc[i][j] = __builtin_amdgcn_mfma_f32_16x16x32_bf16(af[i], bf[j], acc[i][j], 0, 0, 0);
    __builtin_amdgcn_s_setprio(0);
    __builtin_amdgcn_s_barrier();
    __builtin_amdgcn_sched_barrier(0);
    // ---------- phase 1: rows wm*128 + 64..127 (B frags retained) ----------
#pragma unroll
    for (int i = 0; i < 4; ++i) af[i] = *(const bf16x8*)&A[aB + 2048 + i * 512];
    if (pf) STAGE_B(t + 2);
    __builtin_amdgcn_s_barrier();
    __builtin_amdgcn_sched_barrier(0);
    __builtin_amdgcn_s_setprio(1);
#pragma unroll
    for (int i = 0; i < 4; ++i)
#pragma unroll
      for (int j = 0; j < 4; ++j)
        acc[4 + i][j] = __builtin_amdgcn_mfma_f32_16x16x32_bf16(af[i], bf[j], acc[4 + i][j], 0, 0, 0);
    __builtin_amdgcn_s_setprio(0);
    if (t + 1 < T) {
      if (pf) { asm volatile("s_waitcnt vmcnt(4)" ::: "memory"); }   // retire step t+1
      else    { asm volatile("s_waitcnt vmcnt(0)" ::: "memory"); }   // one-time tail drain
    }
    __builtin_amdgcn_s_barrier();
    __builtin_amdgcn_sched_barrier(0);
  }
#undef STAGE_A
#undef STAGE_B

  // ---------- epilogue: C/D col=nl, row=q*4+r ----------
  const int rowq = q * 4;
  if constexpr (P1) {
    const float* b1e = b1 + (size_t)e * FF;
#pragma unroll
    for (int j = 0; j < 4; ++j) {
      const int n = nt * 256 + wn * 64 + j * 16 + nl;
      const float bias = b1e[n];
#pragma unroll
      for (int i = 0; i < 8; ++i) {
        const int m = base + wm * 128 + i * 16 + rowq;
#pragma unroll
        for (int r = 0; r < 4; ++r)
          hout[(size_t)(m + r) * FF + n] = bf16_rne(gelu_tanh(acc[i][j][r] + bias));
      }
    }
  } else {
#pragma unroll
    for (int i = 0; i < 8; ++i) {
      const int m = base + wm * 128 + i * 16 + rowq;
#pragma unroll
      for (int r = 0; r < 4; ++r) {
        float* yrow = ypair + (size_t)(m + r) * HID + nt * 256 + wn * 64;
#pragma unroll
        for (int j = 0; j < 4; ++j) yrow[j * 16 + nl] = acc[i][j][r];
      }
    }
  }
}

// ---------------- combine: out[t] = w0*(y[s0]+b2[e0]) + w1*(y[s1]+b2[e1]) ----
__global__ __launch_bounds__(256) void combine_kernel(
    const float* __restrict__ ypair, const int* __restrict__ slot_of_tok,
    const int* __restrict__ topk_e, const float* __restrict__ topk_w,
    const float* __restrict__ b2, float* __restrict__ out) {
  const int t = blockIdx.x;
  const int tid = threadIdx.x;
  const int s0 = slot_of_tok[2 * t], s1 = slot_of_tok[2 * t + 1];
  const int e0 = topk_e[2 * t], e1 = topk_e[2 * t + 1];
  const float w0 = topk_w[2 * t], w1v = topk_w[2 * t + 1];
  const float4 y0 = ((const float4*)(ypair + (size_t)s0 * HID))[tid];
  const float4 y1 = ((const float4*)(ypair + (size_t)s1 * HID))[tid];
  const float4 c0 = ((const float4*)(b2 + (size_t)e0 * HID))[tid];
  const float4 c1 = ((const float4*)(b2 + (size_t)e1 * HID))[tid];
  float4 o;
  o.x = w0 * (y0.x + c0.x) + w1v * (y1.x + c1.x);
  o.y = w0 * (y0.y + c0.y) + w1v * (y1.y + c1.y);
  o.z = w0 * (y0.z + c0.z) + w1v * (y1.z + c1.z);
  o.w = w0 * (y0.w + c0.w) + w1v * (y1.w + c1.w);
  ((float4*)(out + (size_t)t * HID))[tid] = o;
}

extern "C" void kernel_launch(void* const* d_in, const int* in_sizes, int n_in,
                              void* d_out, int out_size, void* d_ws, size_t ws_size,
                              hipStream_t stream) {
  (void)in_sizes; (void)n_in; (void)ws_size;
  const float* x  = (const float*)d_in[0];
  const float* gw = (const float*)d_in[1];
  const float* gb = (const float*)d_in[2];
  const float* w1 = (const float*)d_in[3];
  const float* b1 = (const float*)d_in[4];
  const float* w2 = (const float*)d_in[5];
  const float* b2 = (const float*)d_in[6];
  float* out = (float*)d_out;

  // ---- workspace layout (total need 303,038,464 B; ws >= 365 MB proven) ----
  char* ws = (char*)d_ws;
  int*   counts  = (int*)(ws + 0);
  int*   cursors = (int*)(ws + 32);
  float* probs   = (float*)(ws + 64);
  int*   offsets = (int*)(ws + 96);
  int*   tok     = (int*)(ws + 4096);      // MAXPAIR ints   -> 77824
  float* wt      = (float*)(ws + 77824);   // MAXPAIR floats -> 151552
  int*   topk_e  = (int*)(ws + 151552);    // -> 217088
  float* topk_w  = (float*)(ws + 217088);  // -> 282624
  int*   slot    = (int*)(ws + 282624);    // -> 348160
  u16*   xb    = (u16*)(ws + 1048576);     // 16,777,216 B -> 17,825,792
  u16*   w1b   = (u16*)(ws + 17825792);    // 67,108,864 B -> 84,934,656
  u16*   w2b   = (u16*)(ws + 84934656);    // 67,108,864 B -> 152,043,520
  u16*   hbuf  = (u16*)(ws + 152043520);   // 150,994,944 B -> 303,038,464
  // ypair overlays xb+w1b (both dead after pass1): 75,497,472 B < 83,886,080
  float* ypair = (float*)(ws + 1048576);

  hipMemsetAsync(ws, 0, 348160, stream);   // header + tok/wt pad slots -> 0

  gate_kernel<<<512, 256, 0, stream>>>(x, gw, gb, counts, probs, topk_e, topk_w);
  finalize_kernel<<<1, 64, 0, stream>>>(counts, cursors, offsets, probs,
                                        out + (out_size - 1));
  scatter_kernel<<<32, 256, 0, stream>>>(topk_e, topk_w, offsets, cursors, tok, wt, slot);
  stream_cvt_kernel<<<8192, 256, 0, stream>>>((const float4*)x, (u16x4*)xb);
  stream_cvt_kernel<<<32768, 256, 0, stream>>>((const float4*)w1, (u16x4*)w1b);
  stream_cvt_kernel<<<32768, 256, 0, stream>>>((const float4*)w2, (u16x4*)w2b);

  const int MT = MAXPAIR / 256;  // 72 M-tiles (blocks past offsets[NEXP] exit)
  moe_gemm<true><<<dim3(FF / 256, MT), 512, 0, stream>>>(
      xb, w1b, b1, tok, offsets, hbuf, nullptr);
  moe_gemm<false><<<dim3(HID / 256, MT), 512, 0, stream>>>(
      hbuf, w2b, nullptr, tok, offsets, nullptr, ypair);
  combine_kernel<<<8192, 256, 0, stream>>>(ypair, slot, topk_e, topk_w, b2, out);
}